// Round 2
// baseline (622.223 us; speedup 1.0000x reference)
//
#include <hip/hip_runtime.h>
#include <hip/hip_bf16.h>
#include <stdint.h>

// ---------------------------------------------------------------------------
// CrossModalAttention: B=2, Tq=Tk=2048, DIM=1024, HEADS=16, HEAD_DIM=64
// Inputs/outputs are FLOAT32 (reference dtype); mask int32. Compute in bf16
// MFMA with f32 accumulation (harness threshold = 2% of max => bf16-tolerant).
// Pipeline:
//   0) cvt: f32 -> bf16 for q,k,v,wq,wk,wv,wo into workspace
//   1) pack_mask: int32 [B,1,Tq,Tk] -> bit mask [B,Tq,Tk/64] (uint64)
//   2) gemm_bt_bias (z=0..2): Q = q@wq^T+bq, K = k@wk^T+bk, V^T = (v@wv^T+bv)^T
//   3) attn_kernel: flash-style fused QK^T -> clip/mask/softmax -> PV
//   4) gemm_bt_bias (f32 out): out = AO@wo^T+bo
// ---------------------------------------------------------------------------

typedef __bf16 bf16;
typedef __bf16 bf16x4 __attribute__((ext_vector_type(4)));
typedef __bf16 bf16x8 __attribute__((ext_vector_type(8)));
typedef float f32x4 __attribute__((ext_vector_type(4)));

#define MFMA_BF16(a, b, c) __builtin_amdgcn_mfma_f32_16x16x32_bf16((a), (b), (c), 0, 0, 0)

#define NEG_INF (-__builtin_inff())

// async global->LDS, 16B per lane. LDS dest is wave-uniform base; HW places
// lane i at base + i*16 (guide §5: no per-lane scatter, no padding).
__device__ __forceinline__ void async_load16(const void* g, void* l) {
  __builtin_amdgcn_global_load_lds((const __attribute__((address_space(1))) void*)g,
                                   (__attribute__((address_space(3))) void*)l, 16, 0, 0);
}

// ---------------------------------------------------------------------------
// 0) f32 -> bf16 conversion. grid = (2048, 7). z selects tensor.
//    z 0..2: 4M elements (q,k,v); z 3..6: 1M elements (wq,wk,wv,wo).
// ---------------------------------------------------------------------------
__global__ __launch_bounds__(256) void cvt_f32_bf16(
    const float* __restrict__ s0, const float* __restrict__ s1, const float* __restrict__ s2,
    const float* __restrict__ s3, const float* __restrict__ s4, const float* __restrict__ s5,
    const float* __restrict__ s6,
    bf16* __restrict__ d0, bf16* __restrict__ d1, bf16* __restrict__ d2,
    bf16* __restrict__ d3, bf16* __restrict__ d4, bf16* __restrict__ d5,
    bf16* __restrict__ d6) {
  const int z = blockIdx.y;
  const float* s = (z == 0) ? s0 : (z == 1) ? s1 : (z == 2) ? s2 : (z == 3) ? s3
                   : (z == 4) ? s4 : (z == 5) ? s5 : s6;
  bf16* d = (z == 0) ? d0 : (z == 1) ? d1 : (z == 2) ? d2 : (z == 3) ? d3
            : (z == 4) ? d4 : (z == 5) ? d5 : d6;
  const int n4 = (z < 3) ? (4 * 1024 * 1024 / 4) : (1024 * 1024 / 4);
  const int stride = gridDim.x * 256;
  for (int i = blockIdx.x * 256 + threadIdx.x; i < n4; i += stride) {
    const float4 v = ((const float4*)s)[i];
    bf16x4 o;
    o[0] = (bf16)v.x; o[1] = (bf16)v.y; o[2] = (bf16)v.z; o[3] = (bf16)v.w;
    ((bf16x4*)d)[i] = o;
  }
}

// ---------------------------------------------------------------------------
// 1) mask bit-pack: one bit per (q,k); wave64 ballot -> one uint64 per 64 cols
// ---------------------------------------------------------------------------
__global__ __launch_bounds__(256) void pack_mask_kernel(const int* __restrict__ mask,
                                                        unsigned long long* __restrict__ bits) {
  const int t = blockIdx.x * 256 + threadIdx.x;
  const int v = mask[t];
  const unsigned long long b = __ballot(v != 0);
  if ((threadIdx.x & 63) == 0) bits[t >> 6] = b;
}

// ---------------------------------------------------------------------------
// 2/4) C[m,n] = sum_k X[m,k] * W[n,k] + bias[n]   (torch Linear, W is [out,in])
// m97 recipe: 128x128 tile, BK=64, global_load_lds(16B), 16x16x32 bf16 MFMA,
// 4 waves each owning a 64x64 (4x4 tiles) patch. z selects X/W/bias/O triple.
// vz: z index whose output is stored per-head-transposed (V^T); -1 none.
// f32out: store f32 to OF instead of bf16 to O (final projection).
// ---------------------------------------------------------------------------
__global__ __launch_bounds__(256) void gemm_bt_bias(
    const bf16* __restrict__ X0, const bf16* __restrict__ X1, const bf16* __restrict__ X2,
    const bf16* __restrict__ W0, const bf16* __restrict__ W1, const bf16* __restrict__ W2,
    const float* __restrict__ Bi0, const float* __restrict__ Bi1, const float* __restrict__ Bi2,
    bf16* __restrict__ O0, bf16* __restrict__ O1, bf16* __restrict__ O2,
    float* __restrict__ OF, int K, int N, int vz, int f32out) {
  const int z = blockIdx.z;
  const bf16* X   = (z == 0) ? X0  : (z == 1) ? X1  : X2;
  const bf16* W   = (z == 0) ? W0  : (z == 1) ? W1  : W2;
  const float* Bi = (z == 0) ? Bi0 : (z == 1) ? Bi1 : Bi2;
  bf16* O         = (z == 0) ? O0  : (z == 1) ? O1  : O2;

  __shared__ bf16 As[128 * 64];  // [row][k], stride 64 (global_load_lds: no pad)
  __shared__ bf16 Bs[128 * 64];

  const int tid = threadIdx.x;
  const int lane = tid & 63;
  const int w = tid >> 6;
  const int la = lane & 15;   // MFMA A/B row index (m or n)
  const int qa = lane >> 4;   // quad
  const int m0 = blockIdx.x * 128;
  const int n0 = blockIdx.y * 128;
  const int wm = (w & 1) * 64;
  const int wn = (w >> 1) * 64;

  f32x4 acc[4][4];
  for (int i = 0; i < 4; ++i)
    for (int j = 0; j < 4; ++j) acc[i][j] = (f32x4){0.f, 0.f, 0.f, 0.f};

  for (int k0 = 0; k0 < K; k0 += 64) {
    // stage A(128x64) and B(128x64): 1024 16B-chunks each, 4 per thread
    for (int i = 0; i < 4; ++i) {
      const int cb = i * 256 + w * 64;  // wave-uniform chunk base
      const int c = cb + lane;
      const int row = c >> 3;
      const int cc = (c & 7) * 8;
      async_load16(X + (size_t)(m0 + row) * K + k0 + cc, As + (size_t)cb * 8);
      async_load16(W + (size_t)(n0 + row) * K + k0 + cc, Bs + (size_t)cb * 8);
    }
    __syncthreads();  // drains vmcnt for global_load_lds
    for (int kk = 0; kk < 64; kk += 32) {
      bf16x8 af[4], bfr[4];
      for (int mt = 0; mt < 4; ++mt)
        af[mt] = *(const bf16x8*)&As[(wm + mt * 16 + la) * 64 + kk + qa * 8];
      for (int nt = 0; nt < 4; ++nt)
        bfr[nt] = *(const bf16x8*)&Bs[(wn + nt * 16 + la) * 64 + kk + qa * 8];
      for (int mt = 0; mt < 4; ++mt)
        for (int nt = 0; nt < 4; ++nt)
          acc[mt][nt] = MFMA_BF16(af[mt], bfr[nt], acc[mt][nt]);
    }
    __syncthreads();
  }

  // epilogue: C/D layout col=lane&15, row=(lane>>4)*4+r (m89-verified)
  const bool vt = (z == vz);
  for (int mt = 0; mt < 4; ++mt)
    for (int nt = 0; nt < 4; ++nt)
      for (int r = 0; r < 4; ++r) {
        const int row = m0 + wm + mt * 16 + qa * 4 + r;
        const int col = n0 + wn + nt * 16 + la;
        const float v = acc[mt][nt][r] + Bi[col];
        if (f32out) {
          OF[(size_t)row * N + col] = v;
        } else if (!vt) {
          O[(size_t)row * N + col] = (bf16)v;
        } else {
          // V^T store: [b][h*64+d][k] ; row = b*2048+k, col = h*64+d
          const int b = row >> 11;
          const int k = row & 2047;
          O[((size_t)(b * 1024 + col)) * 2048 + k] = (bf16)v;
        }
      }
}

// ---------------------------------------------------------------------------
// 3) fused attention. grid = (Tq/128, B*H). 4 waves x 32 q-rows per block.
//    K-tile = 128. Q frags in registers; K/V^T staged in LDS with padded
//    strides (72 / 136 bf16). P: C-layout -> LDS -> A-layout (m120 pattern).
// ---------------------------------------------------------------------------
__global__ __launch_bounds__(256) void attn_kernel(
    const bf16* __restrict__ Qp, const bf16* __restrict__ Kp, const bf16* __restrict__ Vt,
    const unsigned long long* __restrict__ mbits, bf16* __restrict__ AO) {
  __shared__ bf16 Ks[128 * 72];     // [kcol][d]
  __shared__ bf16 Vs[64 * 136];     // [d][kcol]
  __shared__ bf16 Ps[4][16 * 136];  // per-wave P staging: [qrow16][kcol]

  const int tid = threadIdx.x;
  const int lane = tid & 63;
  const int w = tid >> 6;
  const int la = lane & 15;
  const int qa = lane >> 4;
  const int b = blockIdx.y >> 4;
  const int h = blockIdx.y & 15;
  const int q0 = blockIdx.x * 128 + w * 32;  // this wave's 32 q-rows

  // Q fragments: A-operand layout m=lane&15, k=(lane>>4)*8+j
  bf16x8 qf[2][2];
  for (int mt = 0; mt < 2; ++mt)
    for (int kk = 0; kk < 2; ++kk)
      qf[mt][kk] = *(const bf16x8*)&Qp[(size_t)(b * 2048 + q0 + mt * 16 + la) * 1024 +
                                       h * 64 + kk * 32 + qa * 8];

  float mrun[2][4], lrun[2][4], alpha[2][4];
  f32x4 oacc[2][4];
  for (int mt = 0; mt < 2; ++mt)
    for (int r = 0; r < 4; ++r) { mrun[mt][r] = NEG_INF; lrun[mt][r] = 0.f; }
  for (int mt = 0; mt < 2; ++mt)
    for (int d = 0; d < 4; ++d) oacc[mt][d] = (f32x4){0.f, 0.f, 0.f, 0.f};

  for (int kt = 0; kt < 16; ++kt) {
    // --- stage K tile (128 rows x 64 d) and V^T tile (64 d x 128 k) ---
    for (int i = 0; i < 4; ++i) {
      const int c = i * 256 + tid;
      const int krow = c >> 3, kcc = (c & 7) * 8;
      const bf16x8 tk = *(const bf16x8*)&Kp[(size_t)(b * 2048 + kt * 128 + krow) * 1024 + h * 64 + kcc];
      *(bf16x8*)&Ks[krow * 72 + kcc] = tk;
      const int vr = c >> 4, vc = (c & 15) * 8;
      const bf16x8 tv = *(const bf16x8*)&Vt[((size_t)(b * 16 + h) * 64 + vr) * 2048 + kt * 128 + vc];
      *(bf16x8*)&Vs[vr * 136 + vc] = tv;
    }
    __syncthreads();

    // --- S = Q K^T : 32 q-rows x 128 k-cols, contraction d=64 (2 MFMA steps) ---
    f32x4 s[2][8];
    for (int mt = 0; mt < 2; ++mt)
      for (int nt = 0; nt < 8; ++nt) s[mt][nt] = (f32x4){0.f, 0.f, 0.f, 0.f};
    for (int kk = 0; kk < 2; ++kk)
      for (int nt = 0; nt < 8; ++nt) {
        const bf16x8 kf = *(const bf16x8*)&Ks[(nt * 16 + la) * 72 + kk * 32 + qa * 8];
        s[0][nt] = MFMA_BF16(qf[0][kk], kf, s[0][nt]);
        s[1][nt] = MFMA_BF16(qf[1][kk], kf, s[1][nt]);
      }

    // --- scale, clip(+-100), mask, online softmax (per (mt,r) row group) ---
    for (int mt = 0; mt < 2; ++mt)
      for (int r = 0; r < 4; ++r) {
        const int qrow = q0 + mt * 16 + qa * 4 + r;
        const unsigned long long* mrow = mbits + (size_t)(b * 2048 + qrow) * 32 + kt * 2;
        const unsigned long long w0 = mrow[0], w1 = mrow[1];
        float sv[8];
        float mx = NEG_INF;
        for (int nt = 0; nt < 8; ++nt) {
          const int cl = nt * 16 + la;
          const unsigned long long mw = (cl & 64) ? w1 : w0;
          const bool keep = ((mw >> (cl & 63)) & 1ULL) != 0ULL;
          float v = s[mt][nt][r] * 0.125f;                 // 1/sqrt(64)
          v = fminf(100.0f, fmaxf(-100.0f, v));
          v = keep ? v : NEG_INF;
          sv[nt] = v;
          mx = fmaxf(mx, v);
        }
        for (int off = 1; off < 16; off <<= 1) mx = fmaxf(mx, __shfl_xor(mx, off));
        const float nm = fmaxf(mrun[mt][r], mx);
        const float nmu = (nm == NEG_INF) ? 0.0f : nm;  // all-masked guard
        const float al = __expf(mrun[mt][r] - nmu);
        mrun[mt][r] = nm;
        float rs = 0.0f;
        for (int nt = 0; nt < 8; ++nt) {
          const float p = __expf(sv[nt] - nmu);
          rs += p;
          s[mt][nt][r] = p;  // reuse S regs to hold P
        }
        for (int off = 1; off < 16; off <<= 1) rs += __shfl_xor(rs, off);
        lrun[mt][r] = lrun[mt][r] * al + rs;
        alpha[mt][r] = al;
      }

    // --- rescale O accumulators ---
    for (int mt = 0; mt < 2; ++mt)
      for (int d = 0; d < 4; ++d)
        for (int r = 0; r < 4; ++r) oacc[mt][d][r] *= alpha[mt][r];

    // --- P (C-layout) -> LDS -> A-layout, then PV MFMA ---
    for (int mt = 0; mt < 2; ++mt) {
      bf16* pw = Ps[w];
      for (int nt = 0; nt < 8; ++nt)
        for (int r = 0; r < 4; ++r)
          pw[(qa * 4 + r) * 136 + nt * 16 + la] = (bf16)s[mt][nt][r];
      for (int ks = 0; ks < 4; ++ks) {
        const bf16x8 pf = *(const bf16x8*)&pw[la * 136 + ks * 32 + qa * 8];
        for (int d = 0; d < 4; ++d) {
          const bf16x8 vf = *(const bf16x8*)&Vs[(d * 16 + la) * 136 + ks * 32 + qa * 8];
          oacc[mt][d] = MFMA_BF16(pf, vf, oacc[mt][d]);
        }
      }
    }
    __syncthreads();
  }

  // --- epilogue: O / l, store [b, q, h*64+d] bf16 ---
  for (int mt = 0; mt < 2; ++mt)
    for (int d = 0; d < 4; ++d)
      for (int r = 0; r < 4; ++r) {
        const int qrow = q0 + mt * 16 + qa * 4 + r;
        const float v = oacc[mt][d][r] / lrun[mt][r];
        AO[(size_t)(b * 2048 + qrow) * 1024 + h * 64 + d * 16 + la] = (bf16)v;
      }
}

// ---------------------------------------------------------------------------
extern "C" void kernel_launch(void* const* d_in, const int* in_sizes, int n_in,
                              void* d_out, int out_size, void* d_ws, size_t ws_size,
                              hipStream_t stream) {
  const float* q    = (const float*)d_in[0];
  const float* k    = (const float*)d_in[1];
  const float* v    = (const float*)d_in[2];
  const int*   mask = (const int*)d_in[3];
  const float* wq   = (const float*)d_in[4];
  const float* wk   = (const float*)d_in[5];
  const float* wv   = (const float*)d_in[6];
  const float* wo   = (const float*)d_in[7];
  const float* bq   = (const float*)d_in[8];
  const float* bk   = (const float*)d_in[9];
  const float* bv   = (const float*)d_in[10];
  const float* bo   = (const float*)d_in[11];

  // workspace (bf16 elems): qb/AO kb vb (4M ea) | wqb wkb wvb wob (1M ea)
  //                         Qp Kp Vt (4M ea) | mask bits (1 MB). Total 57 MB.
  const size_t M4 = (size_t)4 * 1024 * 1024, M1 = (size_t)1024 * 1024;
  bf16* qb  = (bf16*)d_ws;        // also AO after projections (qb dead then)
  bf16* kb  = qb + M4;
  bf16* vb  = kb + M4;
  bf16* wqb = vb + M4;
  bf16* wkb = wqb + M1;
  bf16* wvb = wkb + M1;
  bf16* wob = wvb + M1;
  bf16* Qp  = wob + M1;
  bf16* Kp  = Qp + M4;
  bf16* Vt  = Kp + M4;
  unsigned long long* mb = (unsigned long long*)(Vt + M4);
  bf16* AO  = qb;
  float* out = (float*)d_out;

  cvt_f32_bf16<<<dim3(2048, 7), dim3(256), 0, stream>>>(
      q, k, v, wq, wk, wv, wo, qb, kb, vb, wqb, wkb, wvb, wob);
  pack_mask_kernel<<<dim3(8388608 / 256), dim3(256), 0, stream>>>(mask, mb);
  gemm_bt_bias<<<dim3(32, 8, 3), dim3(256), 0, stream>>>(
      qb, kb, vb, wqb, wkb, wvb, bq, bk, bv, Qp, Kp, Vt, nullptr, 1024, 1024, 2, 0);
  attn_kernel<<<dim3(16, 32), dim3(256), 0, stream>>>(Qp, Kp, Vt, mb, AO);
  gemm_bt_bias<<<dim3(32, 8, 1), dim3(256), 0, stream>>>(
      AO, AO, AO, wob, wob, wob, bo, bo, bo, nullptr, nullptr, nullptr, out, 1024, 1024, -1, 1);
}